// Round 10
// baseline (208.980 us; speedup 1.0000x reference)
//
#include <hip/hip_runtime.h>
#include <stdint.h>

// BS=2, QLEN=2048, DIM=1024, NH=16, HD=64
#define BSZ  2
#define SEQ  2048
#define DIM  1024
#define NHD  16
#define HD   64
#define MTOT (BSZ*SEQ)   // 4096

using short8  = __attribute__((ext_vector_type(8))) short;   // 8 bf16
using floatx4 = __attribute__((ext_vector_type(4))) float;   // MFMA C/D

#define QSCALE 0.18033688011112042f   // 0.125 * log2(e): softmax in exp2 domain
#define BIGM   1.44e30f               // mask penalty in exp2 domain

__device__ __forceinline__ unsigned short f2bf(float f) {
    unsigned int u = __float_as_uint(f);
    u += 0x7fffu + ((u >> 16) & 1u);     // RNE
    return (unsigned short)(u >> 16);
}
// pack 2 floats -> 2 bf16 (round-half-up) in 3 VALU ops via v_perm_b32
__device__ __forceinline__ unsigned int pk2r(float a, float b) {
    unsigned int ua = __float_as_uint(a) + 0x8000u;
    unsigned int ub = __float_as_uint(b) + 0x8000u;
    return __builtin_amdgcn_perm(ub, ua, 0x07060302);   // {a_hi16, b_hi16}
}

// async global->LDS, 16B per lane; dest is wave-uniform base + lane*16.
__device__ __forceinline__ void gll16(const void* g, const void* lds) {
    unsigned int loff = (unsigned int)(unsigned long long)lds;
    __builtin_amdgcn_global_load_lds(
        (const __attribute__((address_space(1))) unsigned int*)g,
        (__attribute__((address_space(3))) unsigned int*)loff, 16, 0, 0);
}

// ---------------------------------------------------------------------------
// prep: z=0..3 -> W[k][n] fp32 -> Wt[n][k] bf16 (64x64 tiles);
//       z=4    -> X fp32 -> bf16 bulk convert (256 blocks x 16384 elems)
// ---------------------------------------------------------------------------
__global__ __launch_bounds__(256)
void prep(const float* __restrict__ Wq, const float* __restrict__ Wk,
          const float* __restrict__ Wv, const float* __restrict__ Wo,
          const float* __restrict__ X,
          unsigned short* __restrict__ Wt3, unsigned short* __restrict__ Wto,
          unsigned short* __restrict__ Xbf)
{
    const int z = blockIdx.z;
    if (z == 4) {            // X conversion
        const int bid = blockIdx.y * 16 + blockIdx.x;
        size_t base = (size_t)bid * 16384 + threadIdx.x * 8;
#pragma unroll
        for (int j = 0; j < 8; ++j) {
            size_t i = base + (size_t)j * 2048;
            float4 a = *(const float4*)(X + i);
            float4 b = *(const float4*)(X + i + 4);
            uint4 u = {pk2r(a.x, a.y), pk2r(a.z, a.w), pk2r(b.x, b.y), pk2r(b.z, b.w)};
            *(uint4*)(Xbf + i) = u;
        }
        return;
    }
    __shared__ float tile[64 * 65];
    const float* W = (z == 0) ? Wq : (z == 1) ? Wk : (z == 2) ? Wv : Wo;
    unsigned short* out = (z < 3) ? (Wt3 + (size_t)z * DIM * DIM) : Wto;
    const int k0 = blockIdx.x * 64, n0 = blockIdx.y * 64;
    const int t = threadIdx.x;
    const int r = t >> 2, c0 = (t & 3) * 16;
#pragma unroll
    for (int j = 0; j < 4; ++j) {
        float4 v = *(const float4*)&W[(size_t)(k0 + r) * DIM + n0 + c0 + j * 4];
        tile[r * 65 + c0 + j * 4 + 0] = v.x;
        tile[r * 65 + c0 + j * 4 + 1] = v.y;
        tile[r * 65 + c0 + j * 4 + 2] = v.z;
        tile[r * 65 + c0 + j * 4 + 3] = v.w;
    }
    __syncthreads();
    unsigned int p[8];
#pragma unroll
    for (int j = 0; j < 8; ++j)
        p[j] = pk2r(tile[(c0 + 2 * j) * 65 + r], tile[(c0 + 2 * j + 1) * 65 + r]);
    uint4 u0 = {p[0], p[1], p[2], p[3]}, u1 = {p[4], p[5], p[6], p[7]};
    unsigned short* dst = out + (size_t)(n0 + r) * DIM + k0 + c0;
    *(uint4*)dst = u0;
    *(uint4*)(dst + 8) = u1;
}

// ---------------------------------------------------------------------------
// QKV GEMM: 128M x 64N tiles (1536 blocks = 6/CU), BK=32, dbuf two-body
// K-loop.  Wave w owns rows [w*32, w*32+32) x all 64 n.
// Q/K: swapped operands -> packed uint2 stores.  V: transposed sigma layout.
// ---------------------------------------------------------------------------
__global__ __launch_bounds__(256)
void qkv_gemm(const unsigned short* __restrict__ Xbf,
              const unsigned short* __restrict__ Wt3,
              const float* __restrict__ bq, const float* __restrict__ bk,
              const float* __restrict__ bv,
              unsigned short* __restrict__ Qb,
              unsigned short* __restrict__ Kb,
              unsigned short* __restrict__ VbT)
{
    __shared__ unsigned short As[2][128 * 32];
    __shared__ unsigned short Bs[2][64 * 32];

    const int t = threadIdx.x, w = t >> 6, lane = t & 63;
    const int lm = lane & 15, grp = lane >> 4;
    const int m0 = blockIdx.x * 128;
    const int mat = blockIdx.y >> 4;             // 0=Q 1=K 2=V
    const int n0 = (blockIdx.y & 15) * 64;
    const unsigned short* Bg = Wt3 + (size_t)mat * DIM * DIM;
    const int lr = lane >> 2, lc = (lane & 3) * 8;   // 4 lanes/row, 16 rows/gll16
    const bool swap = (mat != 2);

    // running stage pointers (advance 32 elems per tile)
    const unsigned short* xs0 = Xbf + (size_t)(m0 + w * 32 + lr) * DIM + lc;
    const unsigned short* xs1 = xs0 + (size_t)16 * DIM;
    const unsigned short* ws0 = Bg  + (size_t)(n0 + w * 16 + lr) * DIM + lc;

    // hoisted LDS fragment bases (per buffer)
    const unsigned short* afb[2];
    const unsigned short* bfb[2];
#pragma unroll
    for (int u = 0; u < 2; ++u) {
        afb[u] = &As[u][(w * 32 + lm) * 32 + grp * 8];
        bfb[u] = &Bs[u][lm * 32 + grp * 8];
    }

    floatx4 acc[2][4];   // [mt][nt]
#pragma unroll
    for (int i = 0; i < 2; ++i)
#pragma unroll
        for (int j = 0; j < 4; ++j) acc[i][j] = (floatx4){0.f, 0.f, 0.f, 0.f};

#define QKV_STAGE(BUF) do {                                    \
        gll16(xs0, &As[BUF][(w * 32) * 32]);                   \
        gll16(xs1, &As[BUF][(w * 32 + 16) * 32]);              \
        gll16(ws0, &Bs[BUF][(w * 16) * 32]);                   \
        xs0 += 32; xs1 += 32; ws0 += 32;                       \
    } while (0)

#define QKV_BODY(CUR) do {                                                    \
        __syncthreads();                                                      \
        QKV_STAGE(CUR ^ 1);                                                   \
        short8 af[2], bf[4];                                                  \
        _Pragma("unroll")                                                     \
        for (int mt = 0; mt < 2; ++mt)                                        \
            af[mt] = *(const short8*)(afb[CUR] + mt * 512);                   \
        _Pragma("unroll")                                                     \
        for (int nt = 0; nt < 4; ++nt)                                        \
            bf[nt] = *(const short8*)(bfb[CUR] + nt * 512);                   \
        if (swap) {                                                           \
            _Pragma("unroll")                                                 \
            for (int mt = 0; mt < 2; ++mt)                                    \
                _Pragma("unroll")                                             \
                for (int nt = 0; nt < 4; ++nt)                                \
                    acc[mt][nt] = __builtin_amdgcn_mfma_f32_16x16x32_bf16(    \
                        bf[nt], af[mt], acc[mt][nt], 0, 0, 0);                \
        } else {                                                              \
            _Pragma("unroll")                                                 \
            for (int mt = 0; mt < 2; ++mt)                                    \
                _Pragma("unroll")                                             \
                for (int nt = 0; nt < 4; ++nt)                                \
                    acc[mt][nt] = __builtin_amdgcn_mfma_f32_16x16x32_bf16(    \
                        af[mt], bf[nt], acc[mt][nt], 0, 0, 0);                \
        }                                                                     \
    } while (0)

    QKV_STAGE(0);
#pragma unroll 1
    for (int it = 0; it < DIM / 64; ++it) {   // 16 iterations x 2 bodies
        QKV_BODY(0);
        QKV_BODY(1);
    }
#undef QKV_BODY
#undef QKV_STAGE

    if (mat == 2) {          // V -> sigma-permuted + bank-swizzled [bh][d][s]
#pragma unroll
        for (int nt = 0; nt < 4; ++nt) {
            const int c = n0 + nt * 16 + lm;
            const float bb = bv[c];
            const int h = c >> 6, d = c & 63;
#pragma unroll
            for (int mt = 0; mt < 2; ++mt) {
                const int r = m0 + w * 32 + mt * 16 + grp * 4;
                const int b = r >> 11, s = r & 2047;
                const int si = s & 63, sb = s & ~63;
                const int cg = si >> 4, g = (si >> 2) & 3;
                const int unit = (((cg & 1) << 2) | g) ^ (d & 7);   // + bank XOR
                const int sph = sb + unit * 8 + ((cg >> 1) << 2);
                uint2 pv;
                pv.x = pk2r(acc[mt][nt][0] + bb, acc[mt][nt][1] + bb);
                pv.y = pk2r(acc[mt][nt][2] + bb, acc[mt][nt][3] + bb);
                *(uint2*)&VbT[(((size_t)(b * NHD + h)) * HD + d) * SEQ + sph] = pv;
            }
        }
    } else {                 // Q/K swapped epilogue: packed 4-channel stores
        const float* bias = (mat == 0) ? bq : bk;
        unsigned short* dst = (mat == 0) ? Qb : Kb;
        const float sc = (mat == 0) ? QSCALE : 1.0f;
#pragma unroll
        for (int nt = 0; nt < 4; ++nt) {
            const int c0 = n0 + nt * 16 + grp * 4;   // 4 consecutive c
            float4 bb = *(const float4*)&bias[c0];
            const int h = c0 >> 6, d0 = c0 & 63;
#pragma unroll
            for (int mt = 0; mt < 2; ++mt) {
                const int r = m0 + w * 32 + mt * 16 + lm;
                const int b = r >> 11, s = r & 2047;
                uint2 pv;
                pv.x = pk2r((acc[mt][nt][0] + bb.x) * sc, (acc[mt][nt][1] + bb.y) * sc);
                pv.y = pk2r((acc[mt][nt][2] + bb.z) * sc, (acc[mt][nt][3] + bb.w) * sc);
                const int dd = (mat == 0) ? d0
                             : ((((d0 >> 3) ^ (s & 7)) << 3) | (d0 & 7));
                *(uint2*)&dst[(((size_t)(b * NHD + h)) * SEQ + s) * HD + dd] = pv;
            }
        }
    }
}

// ---------------------------------------------------------------------------
// Flash attention v9 (unchanged from R9): dbuf gll16 K-loop, 1 barrier/iter,
// register-only P via sigma-permuted V, LDS mask table, two-body loop.
// ---------------------------------------------------------------------------
__global__ __launch_bounds__(256, 4)
void attn(const unsigned short* __restrict__ Qb,
          const unsigned short* __restrict__ Kb,
          const unsigned short* __restrict__ VbT,
          const float* __restrict__ mask,
          unsigned short* __restrict__ Cb)
{
    __shared__ unsigned short Kt[2][64 * 64];  // [key][d_sw]
    __shared__ unsigned short Vt[2][64 * 64];  // [d][key sigma+sw]
    __shared__ float Msk[SEQ];                 // exp2-domain additive penalty

    const int t = threadIdx.x, w = t >> 6, lane = t & 63;
    const int lm = lane & 15, grp = lane >> 4;
    const int x7 = lm & 7;
    const int bh = blockIdx.y, b = bh >> 4, h = bh & 15;
    const int q0 = blockIdx.x * 64;

    short8 qf[2];
    {
        const unsigned short* qrow = Qb + ((size_t)bh * SEQ + q0 + w * 16 + lm) * HD;
        qf[0] = *(const short8*)(qrow + grp * 8);
        qf[1] = *(const short8*)(qrow + 32 + grp * 8);
    }

    {   // stage mask -> additive penalties (one-time; first barrier publishes)
        const float* mb = mask + b * SEQ;
        const int i = t * 8;
        float4 a = *(const float4*)(mb + i);
        float4 c = *(const float4*)(mb + i + 4);
        float4 ra = {__builtin_fmaf(a.x, BIGM, -BIGM), __builtin_fmaf(a.y, BIGM, -BIGM),
                     __builtin_fmaf(a.z, BIGM, -BIGM), __builtin_fmaf(a.w, BIGM, -BIGM)};
        float4 rc = {__builtin_fmaf(c.x, BIGM, -BIGM), __builtin_fmaf(c.y, BIGM, -BIGM),
                     __builtin_fmaf(c.z, BIGM, -BIGM), __builtin_fmaf(c.w, BIGM, -BIGM)};
        *(float4*)&Msk[i]     = ra;
        *(float4*)&Msk[i + 4] = rc;
    }

    floatx4 oacc[4];
#pragma unroll
    for (int i = 0; i < 4; ++i) oacc[i] = (floatx4){0.f, 0.f, 0.f, 0.f};
    float lpart = 0.f;

    const unsigned short* Kg = Kb + (size_t)bh * SEQ * HD;
    const unsigned short* Vg = VbT + (size_t)bh * HD * SEQ;
    const int srow = lane >> 3, scol = (lane & 7) * 8;

    const unsigned short* kp0 = Kg + (size_t)(w * 16 + srow) * HD + scol;
    const unsigned short* kp1 = kp0 + 8 * HD;
    const unsigned short* vp0 = Vg + (size_t)(w * 16 + srow) * SEQ + scol;
    const unsigned short* vp1 = vp0 + 8 * SEQ;

    gll16(kp0, &Kt[0][(w * 16) * 64]);
    gll16(kp1, &Kt[0][(w * 16 + 8) * 64]);
    gll16(vp0, &Vt[0][(w * 16) * 64]);
    gll16(vp1, &Vt[0][(w * 16 + 8) * 64]);
    kp0 += 64 * HD; kp1 += 64 * HD; vp0 += 64; vp1 += 64;

    const unsigned short* kba[2]; const unsigned short* kbb[2];
    const unsigned short* vba[2]; const unsigned short* vbb[2];
#pragma unroll
    for (int u = 0; u < 2; ++u) {
        kba[u] = &Kt[u][lm * 64 + ((grp    ) ^ x7) * 8];
        kbb[u] = &Kt[u][lm * 64 + ((4 + grp) ^ x7) * 8];
        vba[u] = &Vt[u][lm * 64 + ((grp    ) ^ x7) * 8];
        vbb[u] = &Vt[u][lm * 64 + ((4 + grp) ^ x7) * 8];
    }
    const float* mp = &Msk[grp * 4];

#define ATTN_BODY(CUR) do {                                                   \
        __syncthreads();                                                      \
        gll16(kp0, &Kt[CUR ^ 1][(w * 16) * 64]);                              \
        gll16(kp1, &Kt[CUR ^ 1][(w * 16 + 8) * 64]);                          \
        gll16(vp0, &Vt[CUR ^ 1][(w * 16) * 64]);                              \
        gll16(vp1, &Vt[CUR ^ 1][(w * 16 + 8) * 64]);                          \
        kp0 += 64 * HD; kp1 += 64 * HD; vp0 += 64; vp1 += 64;                 \
        floatx4 sv[4];                                                        \
        _Pragma("unroll")                                                     \
        for (int cg = 0; cg < 4; ++cg) {                                      \
            short8 a0 = *(const short8*)(kba[CUR] + cg * 1024);               \
            short8 a1 = *(const short8*)(kbb[CUR] + cg * 1024);               \
            floatx4 s = (floatx4){0.f, 0.f, 0.f, 0.f};                        \
            s = __builtin_amdgcn_mfma_f32_16x16x32_bf16(a0, qf[0], s, 0, 0, 0); \
            s = __builtin_amdgcn_mfma_f32_16x16x32_bf16(a1, qf[1], s, 0, 0, 0); \
            sv[cg] = s;                                                       \
        }                                                                     \
        short8 vf[4][2];                                                      \
        _Pragma("unroll")                                                     \
        for (int dg = 0; dg < 4; ++dg) {                                      \
            vf[dg][0] = *(const short8*)(vba[CUR] + dg * 1024);               \
            vf[dg][1] = *(const short8*)(vbb[CUR] + dg * 1024);               \
        }                                                                     \
        float p[4][4];                                                        \
        _Pragma("unroll")                                                     \
        for (int cg = 0; cg < 4; ++cg) {                                      \
            float4 md = *(const float4*)(mp + cg * 16);                       \
            p[cg][0] = __builtin_exp2f(sv[cg][0] + md.x);                     \
            p[cg][1] = __builtin_exp2f(sv[cg][1] + md.y);                     \
            p[cg][2] = __builtin_exp2f(sv[cg][2] + md.z);                     \
            p[cg][3] = __builtin_exp2f(sv[cg][3] + md.w);                     \
            lpart += (p[cg][0] + p[cg][1]) + (p[cg][2] + p[cg][3]);           \
        }                                                                     \
        mp += 64;                                                             \
        uint4 u0, u1;                                                         \
        u0.x = pk2r(p[0][0], p[0][1]); u0.y = pk2r(p[0][2], p[0][3]);         \
        u0.z = pk2r(p[2][0], p[2][1]); u0.w = pk2r(p[2][2], p[2][3]);         \
        u1.x = pk2r(p[1][0], p[1][1]); u1.y = pk2r(p[1][2], p[1][3]);         \
        u1.z = pk2r(p[3][0], p[3][1]); u1.w = pk2r(p[3][2], p[3][3]);         \
        short8 ap0 = *(const short8*)&u0;                                     \
        short8 ap1 = *(const short8*)&u1;                                     \
        _Pragma("unroll")                                                     \
        for (int dg = 0; dg < 4; ++dg) {                                      \
            oacc[dg] = __builtin_amdgcn_mfma_f32_16x16x32_bf16(ap0, vf[dg][0], oacc[dg], 0, 0, 0); \
            oacc[dg] = __builtin_amdgcn_mfma_f32_16x16x32_bf16(ap1, vf[dg][1], oacc[dg], 0, 0, 0); \
        }                                                                     \
    } while (0)

#pragma unroll 1
    for (int it = 0; it < SEQ / 128; ++it) {
        ATTN_BODY(0);
        ATTN_BODY(1);
    }
#undef ATTN_BODY

    lpart += __shfl_xor(lpart, 16);
    lpart += __shfl_xor(lpart, 32);
    const float linv = (lpart > 0.f) ? 1.0f / lpart : 0.f;
    float inv[4];
#pragma unroll
    for (int r = 0; r < 4; ++r) inv[r] = __shfl(linv, grp * 4 + r);
#pragma unroll
    for (int dg = 0; dg < 4; ++dg)
#pragma unroll
        for (int r = 0; r < 4; ++r) {
            const int s = q0 + w * 16 + grp * 4 + r;
            Cb[((size_t)(b * SEQ + s)) * DIM + h * HD + dg * 16 + lm] =
                f2bf(oacc[dg][r] * inv[r]);
        }
}

// ---------------------------------------------------------------------------
// out = ctx @ Wo + bo: 128Mx64N, dbuf two-body K-loop, swapped operands,
// float4 stores.  (unchanged from R9)
// ---------------------------------------------------------------------------
__global__ __launch_bounds__(256)
void out_gemm(const unsigned short* __restrict__ Cb,
              const unsigned short* __restrict__ Wto,
              const float* __restrict__ bo,
              float* __restrict__ out)
{
    __shared__ unsigned short As[2][128 * 32];
    __shared__ unsigned short Bs[2][64 * 32];

    const int t = threadIdx.x, w = t >> 6, lane = t & 63;
    const int lm = lane & 15, grp = lane >> 4;
    const int m0 = blockIdx.x * 128;
    const int n0 = blockIdx.y * 64;
    const int lr = lane >> 2, lc = (lane & 3) * 8;
    const int r0 = w * 16;

    const unsigned short* cs0 = Cb  + (size_t)(m0 + r0 + lr) * DIM + lc;
    const unsigned short* cs1 = Cb  + (size_t)(m0 + 64 + r0 + lr) * DIM + lc;
    const unsigned short* ws0 = Wto + (size_t)(n0 + r0 + lr) * DIM + lc;

    const unsigned short* afb[2];
    const unsigned short* bfb[2];
#pragma unroll
    for (int u = 0; u < 2; ++u) {
        afb[u] = &As[u][(w * 32 + lm) * 32 + grp * 8];
        bfb[u] = &Bs[u][lm * 32 + grp * 8];
    }

    floatx4 acc[2][4];
#pragma unroll
    for (int i = 0; i < 2; ++i)
#pragma unroll
        for (int j = 0; j < 4; ++j) acc[i][j] = (floatx4){0.f, 0.f, 0.f, 0.f};

#define OUT_STAGE(BUF) do {                                    \
        gll16(cs0, &As[BUF][r0 * 32]);                         \
        gll16(cs1, &As[BUF][(64 + r0) * 32]);                  \
        gll16(ws0, &Bs[BUF][r0 * 32]);                         \
        cs0 += 32; cs1 += 32; ws0 += 32;                       \
    } while (0)

#define OUT_BODY(CUR) do {                                                    \
        __syncthreads();                                                      \
        OUT_STAGE(CUR ^ 1);                                                   \
        short8 af[2], bf[4];                                                  \
        _Pragma("unroll")                                                     \
        for (int mt = 0; mt < 2; ++mt)                                        \
            af[mt] = *(const short8*)(afb[CUR] + mt * 512);                   \
        _Pragma("unroll")                                                     \
        for (int nt = 0; nt < 4; ++nt)                                        \
            bf[nt] = *(const short8*)(bfb[CUR] + nt * 512);                   \
        _Pragma("unroll")                                                     \
        for (int mt = 0; mt < 2; ++mt)                                        \
            _Pragma("unroll")                                                 \
            for (int nt = 0; nt < 4; ++nt)                                    \
                acc[mt][nt] = __builtin_amdgcn_mfma_f32_16x16x32_bf16(        \
                    bf[nt], af[mt], acc[mt][nt], 0, 0, 0);                    \
    } while (0)

    OUT_STAGE(0);
#pragma unroll 1
    for (int it = 0; it < DIM / 64; ++it) {
        OUT_BODY(0);
        OUT_BODY(1);
    }
#undef OUT_BODY
#undef OUT_STAGE

#pragma unroll
    for (int nt = 0; nt < 4; ++nt) {
        const int c0 = n0 + nt * 16 + grp * 4;
        float4 bb = *(const float4*)&bo[c0];
#pragma unroll
        for (int mt = 0; mt < 2; ++mt) {
            const int r = m0 + w * 32 + mt * 16 + lm;
            float4 o = {acc[mt][nt][0] + bb.x, acc[mt][nt][1] + bb.y,
                        acc[mt][nt][2] + bb.z, acc[mt][nt][3] + bb.w};
            *(float4*)&out[(size_t)r * DIM + c0] = o;
        }
    }
}

// ---------------------------------------------------------------------------
extern "C" void kernel_launch(void* const* d_in, const int* in_sizes, int n_in,
                              void* d_out, int out_size, void* d_ws, size_t ws_size,
                              hipStream_t stream)
{
    const float* x    = (const float*)d_in[0];
    const float* mask = (const float*)d_in[1];
    const float* Wq   = (const float*)d_in[2];
    const float* bq   = (const float*)d_in[3];
    const float* Wk   = (const float*)d_in[4];
    const float* bk   = (const float*)d_in[5];
    const float* Wv   = (const float*)d_in[6];
    const float* bv   = (const float*)d_in[7];
    const float* Wo   = (const float*)d_in[8];
    const float* bo   = (const float*)d_in[9];
    float* out = (float*)d_out;

    const size_t M1 = (size_t)DIM * DIM;           // 1M elems
    unsigned short* Qb  = (unsigned short*)d_ws;   // 4M elems each
    unsigned short* Kb  = Qb  + 4 * M1;
    unsigned short* VbT = Kb  + 4 * M1;
    unsigned short* Cb  = VbT + 4 * M1;
    unsigned short* Xbf = Cb  + 4 * M1;
    unsigned short* Wt3 = Xbf + 4 * M1;            // 3M elems
    unsigned short* Wto = Wt3 + 3 * M1;            // 1M elems  (48 MB total)

    prep<<<dim3(16, 16, 5), 256, 0, stream>>>(Wq, Wk, Wv, Wo, x, Wt3, Wto, Xbf);
    qkv_gemm<<<dim3(MTOT / 128, 48), 256, 0, stream>>>(Xbf, Wt3, bq, bk, bv, Qb, Kb, VbT);
    attn<<<dim3(SEQ / 64, BSZ * NHD), 256, 0, stream>>>(Qb, Kb, VbT, mask, Cb);
    out_gemm<<<dim3(MTOT / 128, DIM / 64), 256, 0, stream>>>(Cb, Wto, bo, out);
}